// Round 2
// baseline (821.565 us; speedup 1.0000x reference)
//
#include <hip/hip_runtime.h>

// CrossAttentionSpatial: GN(x), GN(condA), Q/K/V 1x1 convs, 4096x4096 attention.
// fp16 MFMA (16x16x32) throughout; fp32 accumulate; no-max-sub online softmax.
// B=8, C=256, E=512, N=M=4096, GROUPS=32.
//
// R2: attention rebuilt as global-fragment flash kernel. K/V fragments are
// direct 16B global loads (L1/L2-served, 0.5 loads/MFMA via 2x2 register
// blocking); LDS holds only P (16KB double-buffered, 1 barrier/iter).
// S^T = K*Q^T orientation makes P-writes 8B-vectorized.

typedef _Float16 half8 __attribute__((ext_vector_type(8)));
typedef _Float16 half4v __attribute__((ext_vector_type(4)));
typedef float f32x4 __attribute__((ext_vector_type(4)));

#define MFMA16(a, b, c) __builtin_amdgcn_mfma_f32_16x16x32_f16((a), (b), (c), 0, 0, 0)

// ---------------------------------------------------------------------------
// Kernel 1: group stats. Groups are contiguous segments: x: 256 groups x 32768
// floats; condA: 256 groups x 65536. One block per group.
// ---------------------------------------------------------------------------
__global__ __launch_bounds__(256) void stats_kernel(
    const float* __restrict__ x, const float* __restrict__ condA,
    float* __restrict__ sx, float* __restrict__ sc) {
  int id = blockIdx.x;
  const float4* src;
  int nf4;
  float* dst;
  float inv_n;
  if (id < 256) {
    src = (const float4*)(x + (size_t)id * 32768);
    nf4 = 8192;
    dst = sx + id * 2;
    inv_n = 1.0f / 32768.0f;
  } else {
    int j = id - 256;
    src = (const float4*)(condA + (size_t)j * 65536);
    nf4 = 16384;
    dst = sc + j * 2;
    inv_n = 1.0f / 65536.0f;
  }
  int t = threadIdx.x;
  float s = 0.f, s2 = 0.f;
  for (int i = t; i < nf4; i += 256) {
    float4 v = src[i];
    s += v.x + v.y + v.z + v.w;
    s2 += v.x * v.x + v.y * v.y + v.z * v.z + v.w * v.w;
  }
#pragma unroll
  for (int m = 1; m <= 32; m <<= 1) {
    s += __shfl_xor(s, m, 64);
    s2 += __shfl_xor(s2, m, 64);
  }
  __shared__ float red[8];
  int w = t >> 6;
  if ((t & 63) == 0) { red[w * 2] = s; red[w * 2 + 1] = s2; }
  __syncthreads();
  if (t == 0) {
    float S = red[0] + red[2] + red[4] + red[6];
    float S2 = red[1] + red[3] + red[5] + red[7];
    float mu = S * inv_n;
    float var = S2 * inv_n - mu * mu;
    dst[0] = mu;
    dst[1] = rsqrtf(var + 1e-5f);
  }
}

// ---------------------------------------------------------------------------
// Kernel 2: normalize + transpose. src [B][CH][4096] fp32 -> dst [B][4096][CH]
// fp16.  64x64 tile via LDS (row pad 65 -> conflict-free scalar ops).
// ---------------------------------------------------------------------------
template <int CH, int GS>
__global__ __launch_bounds__(256) void ntrans_kernel(
    const float* __restrict__ src, const float* __restrict__ stats,
    const float* __restrict__ gw, const float* __restrict__ gb,
    _Float16* __restrict__ dst) {
  int bid = blockIdx.x;
  int b = bid & 7, nt = (bid >> 3) & 63, ctile = bid >> 9;
  int n0 = nt * 64, c0 = ctile * 64;
  int t = threadIdx.x;
  __shared__ float tile[64][65];

  int cl = t >> 2;  // 0..63 (channel within tile)
  int c = c0 + cl;
  const float* st = stats + ((size_t)b * 32 + (c / GS)) * 2;
  float mu = st[0], rs = st[1];
  float a = rs * gw[c];
  float bb = gb[c] - mu * a;
  const float* srow = src + ((size_t)(b * CH + c)) * 4096 + n0 + (t & 3) * 16;
#pragma unroll
  for (int i = 0; i < 4; i++) {
    float4 v = *(const float4*)(srow + 4 * i);
    int nn = (t & 3) * 16 + 4 * i;
    tile[cl][nn + 0] = v.x * a + bb;
    tile[cl][nn + 1] = v.y * a + bb;
    tile[cl][nn + 2] = v.z * a + bb;
    tile[cl][nn + 3] = v.w * a + bb;
  }
  __syncthreads();
  int nl = t >> 2;  // row of output
  half8 o0v, o1v;
#pragma unroll
  for (int i = 0; i < 8; i++) o0v[i] = (_Float16)tile[(t & 3) * 16 + i][nl];
#pragma unroll
  for (int i = 0; i < 8; i++) o1v[i] = (_Float16)tile[(t & 3) * 16 + 8 + i][nl];
  _Float16* drow = dst + ((size_t)b * 4096 + n0 + nl) * CH + c0 + (t & 3) * 16;
  *(half8*)drow = o0v;
  *((half8*)drow + 1) = o1v;
}

// ---------------------------------------------------------------------------
// Kernel 3: weight fp32 -> fp16.
// ---------------------------------------------------------------------------
__global__ __launch_bounds__(256) void wconv_kernel(
    const float* __restrict__ wq, const float* __restrict__ wk,
    const float* __restrict__ wv, _Float16* __restrict__ dq,
    _Float16* __restrict__ dk, _Float16* __restrict__ dv) {
  int i = blockIdx.x * 256 + threadIdx.x;
  if (i < 65536) dq[i] = (_Float16)wq[i];
  int j = i - 65536;
  if (j >= 0 && j < 131072) dk[j] = (_Float16)wk[j];
  int k = i - 196608;
  if (k >= 0 && k < 131072) dv[k] = (_Float16)wv[k];
}

// ---------------------------------------------------------------------------
// Kernel 4: projection GEMM, LDS-free (unchanged from R1).
// MODE 0: Q (scaled 1/16), [B][N][256]. MODE 1: K, [B][N][256].
// MODE 2: V, [B][256][N] channel-major.
// ---------------------------------------------------------------------------
template <int CIN, int MODE>
__global__ __launch_bounds__(256, 2) void proj_kernel(
    const _Float16* __restrict__ A, const _Float16* __restrict__ W,
    const float* __restrict__ bias, _Float16* __restrict__ out) {
  int bid = blockIdx.x;
  int b = bid & 7, nt = (bid >> 3) & 63, ot = bid >> 9;
  int n0 = nt * 64, o0 = ot * 128;
  int t = threadIdx.x, l = t & 63, w = t >> 6;
  int c15 = l & 15, q = l >> 4;
  int row = n0 + w * 16 + c15;

  const half8* arow = (const half8*)(A + ((size_t)b * 4096 + row) * CIN) + q;
  const half8* wrows[8];
#pragma unroll
  for (int ct = 0; ct < 8; ct++)
    wrows[ct] = (const half8*)(W + (size_t)(o0 + ct * 16 + c15) * CIN) + q;

  f32x4 acc[8] = {};
#pragma unroll 4
  for (int ks = 0; ks < CIN / 32; ks++) {
    half8 af = arow[ks * 4];
#pragma unroll
    for (int ct = 0; ct < 8; ct++) {
      half8 bf = wrows[ct][ks * 4];
      acc[ct] = MFMA16(af, bf, acc[ct]);
    }
  }
#pragma unroll
  for (int ct = 0; ct < 8; ct++) {
    int o = o0 + ct * 16 + c15;
    float bs = bias[o];
    if constexpr (MODE == 2) {
      half4v pv4;
#pragma unroll
      for (int r = 0; r < 4; r++) pv4[r] = (_Float16)(acc[ct][r] + bs);
      *(half4v*)(out + ((size_t)b * 256 + o) * 4096 + n0 + w * 16 + 4 * q) = pv4;
    } else {
#pragma unroll
      for (int r = 0; r < 4; r++) {
        float v = acc[ct][r] + bs;
        if constexpr (MODE == 0) v *= 0.0625f;  // 1/sqrt(C)
        out[((size_t)b * 4096 + n0 + w * 16 + 4 * q + r) * 256 + o] = (_Float16)v;
      }
    }
  }
}

// ---------------------------------------------------------------------------
// Kernel 5 (R2): global-fragment flash attention.
// Block: 64 Q-rows (n), loop m in 64-row tiles. 4 waves: S-phase wave =
// (mh = w&1) m-half x (nh = w>>1) n-half -> 2x2 16-tiles, K frags direct from
// global (each shared by 2 MFMAs). S^T = K*Q^T so C-layout holds 4 consecutive
// m per lane -> vector 8B P store. PV: wave = nh x (c-half = w&1): A = P from
// LDS (16B swizzled b128), B = V frags direct from global ([C][M] layout ->
// contiguous). One barrier/iter (double-buffered P). Out fp32 [B][C][N].
// Grid 512, b = bid&7 (same-batch blocks share XCD L2; K+V/batch = 4.2MB).
// ---------------------------------------------------------------------------
__global__ __launch_bounds__(256, 2) void attn_kernel(
    const _Float16* __restrict__ Q, const _Float16* __restrict__ K,
    const _Float16* __restrict__ V, float* __restrict__ out) {
  int bid = blockIdx.x;
  int b = bid & 7, nt = bid >> 3;
  int n0 = nt * 64;
  int t = threadIdx.x, l = t & 63, w = t >> 6;
  int c15 = l & 15, q = l >> 4;
  int mh = w & 1, nh = w >> 1;  // S: m-half; PV: c-half = mh

  __shared__ __align__(16) _Float16 pbuf[2][64 * 64];  // 16 KB, dbuf
  __shared__ float lsw[2][64];

  // Q B-frags (loaded once): n = n0 + nh*32 + tt*16 + c15, ch granule q+4ks
  half8 qf[2][8];
#pragma unroll
  for (int tt = 0; tt < 2; tt++) {
    const half8* qrow =
        (const half8*)(Q + ((size_t)b * 4096 + n0 + nh * 32 + tt * 16 + c15) * 256) + q;
#pragma unroll
    for (int ks = 0; ks < 8; ks++) qf[tt][ks] = qrow[ks * 4];
  }

  f32x4 acc_o[2][8] = {};
  float l_part[2] = {0.f, 0.f};

  // K row pointers: rows mh*32 + mt*16 + c15 (+64/iter), granule q + 4ks
  const half8* krow[2];
#pragma unroll
  for (int mt = 0; mt < 2; mt++)
    krow[mt] = (const half8*)(K + ((size_t)b * 4096 + mh * 32 + mt * 16 + c15) * 256) + q;
  // V row pointers: channel c = mh*128 + ct*16 + c15, m-granule q (+8/iter)
  const half8* vrow[8];
#pragma unroll
  for (int ct = 0; ct < 8; ct++)
    vrow[ct] = (const half8*)(V + ((size_t)b * 256 + mh * 128 + ct * 16 + c15) * 4096) + q;

#pragma unroll 2
  for (int it = 0; it < 64; it++) {
    // Prefetch half the V frags (ms=0) to hide latency under S-phase
    half8 vf0[8];
#pragma unroll
    for (int ct = 0; ct < 8; ct++) vf0[ct] = vrow[ct][0];

    // ---- S^T = K Q^T : wave computes [32m x 32n] as 2x2 16-tiles ----
    f32x4 s[2][2] = {};
#pragma unroll
    for (int ks = 0; ks < 8; ks++) {
      half8 kf0 = krow[0][ks * 4];
      half8 kf1 = krow[1][ks * 4];
      s[0][0] = MFMA16(kf0, qf[0][ks], s[0][0]);
      s[0][1] = MFMA16(kf0, qf[1][ks], s[0][1]);
      s[1][0] = MFMA16(kf1, qf[0][ks], s[1][0]);
      s[1][1] = MFMA16(kf1, qf[1][ks], s[1][1]);
    }
    krow[0] += 64 * 32;  // advance 64 m-rows
    krow[1] += 64 * 32;

    // ---- P = exp(S^T), accumulate l, store P (8B vector, swizzled) ----
    _Float16* pb = pbuf[it & 1];
#pragma unroll
    for (int mt = 0; mt < 2; mt++)
#pragma unroll
      for (int tt = 0; tt < 2; tt++) {
        half4v pv;
        float ac = 0.f;
#pragma unroll
        for (int r = 0; r < 4; r++) {
          float e = __expf(s[mt][tt][r]);
          ac += e;
          pv[r] = (_Float16)e;
        }
        l_part[tt] += ac;
        int n = nh * 32 + tt * 16 + c15;
        int m04 = mh * 32 + mt * 16 + 4 * q;
        int g = (m04 >> 3) ^ (n & 7);
        *(half4v*)&pb[n * 64 + g * 8 + (m04 & 7)] = pv;
      }
    __syncthreads();  // the only barrier per iter

    // ---- PV: O[n][c] += P V, wave = [32n x 128c] ----
    half8 vf1[8];
#pragma unroll
    for (int ct = 0; ct < 8; ct++) {
      vf1[ct] = vrow[ct][4];
      vrow[ct] += 8;  // advance 64 m
    }
    half8 pf[2][2];
#pragma unroll
    for (int tt = 0; tt < 2; tt++) {
      int n = nh * 32 + tt * 16 + c15;
#pragma unroll
      for (int ms = 0; ms < 2; ms++) {
        int g = (4 * ms + q) ^ (n & 7);
        pf[tt][ms] = *(const half8*)&pb[n * 64 + g * 8];
      }
    }
#pragma unroll
    for (int ct = 0; ct < 8; ct++) {
      acc_o[0][ct] = MFMA16(pf[0][0], vf0[ct], acc_o[0][ct]);
      acc_o[1][ct] = MFMA16(pf[1][0], vf0[ct], acc_o[1][ct]);
    }
#pragma unroll
    for (int ct = 0; ct < 8; ct++) {
      acc_o[0][ct] = MFMA16(pf[0][1], vf1[ct], acc_o[0][ct]);
      acc_o[1][ct] = MFMA16(pf[1][1], vf1[ct], acc_o[1][ct]);
    }
  }

  // ---- epilogue: combine l across q-quads and the two m-half waves ----
#pragma unroll
  for (int tt = 0; tt < 2; tt++) {
    float v = l_part[tt];
    v += __shfl_xor(v, 16, 64);
    v += __shfl_xor(v, 32, 64);
    l_part[tt] = v;
  }
  if (l < 16) {
    lsw[mh][nh * 32 + c15] = l_part[0];
    lsw[mh][nh * 32 + 16 + c15] = l_part[1];
  }
  __syncthreads();
#pragma unroll
  for (int tt = 0; tt < 2; tt++) {
    float linv[4];
#pragma unroll
    for (int r = 0; r < 4; r++) {
      int nloc = nh * 32 + tt * 16 + 4 * q + r;
      linv[r] = 1.0f / (lsw[0][nloc] + lsw[1][nloc]);
    }
#pragma unroll
    for (int ct = 0; ct < 8; ct++) {
      int c = mh * 128 + ct * 16 + c15;
      float4 o4;
      o4.x = acc_o[tt][ct][0] * linv[0];
      o4.y = acc_o[tt][ct][1] * linv[1];
      o4.z = acc_o[tt][ct][2] * linv[2];
      o4.w = acc_o[tt][ct][3] * linv[3];
      *(float4*)(out + ((size_t)b * 256 + c) * 4096 + n0 + nh * 32 + tt * 16 + 4 * q) = o4;
    }
  }
}

// ---------------------------------------------------------------------------
extern "C" void kernel_launch(void* const* d_in, const int* in_sizes, int n_in,
                              void* d_out, int out_size, void* d_ws,
                              size_t ws_size, hipStream_t stream) {
  const float* x = (const float*)d_in[0];
  const float* condA = (const float*)d_in[1];
  const float* gxw = (const float*)d_in[2];
  const float* gxb = (const float*)d_in[3];
  const float* gcw = (const float*)d_in[4];
  const float* gcb = (const float*)d_in[5];
  const float* qw = (const float*)d_in[6];
  const float* qb = (const float*)d_in[7];
  const float* kw = (const float*)d_in[8];
  const float* kb = (const float*)d_in[9];
  const float* vw = (const float*)d_in[10];
  const float* vb = (const float*)d_in[11];
  float* out = (float*)d_out;

  char* ws = (char*)d_ws;
  float* statsx = (float*)(ws);                     // 2048 B
  float* statsc = (float*)(ws + 2048);              // 2048 B
  _Float16* wqh = (_Float16*)(ws + 4096);           // 128 KB
  _Float16* wkh = (_Float16*)(ws + 135168);         // 256 KB
  _Float16* wvh = (_Float16*)(ws + 397312);         // 256 KB
  char* p = ws + 659456;
  _Float16* hxT = (_Float16*)p; p += (size_t)8 * 4096 * 256 * 2;  // 16 MB
  _Float16* h1T = (_Float16*)p; p += (size_t)8 * 4096 * 512 * 2;  // 32 MB
  _Float16* Qh = (_Float16*)p;  p += (size_t)8 * 4096 * 256 * 2;  // 16 MB
  _Float16* Kh = (_Float16*)p;  p += (size_t)8 * 4096 * 256 * 2;  // 16 MB
  _Float16* Vh = (_Float16*)p;                                    // 16 MB

  stats_kernel<<<512, 256, 0, stream>>>(x, condA, statsx, statsc);
  ntrans_kernel<256, 8><<<2048, 256, 0, stream>>>(x, statsx, gxw, gxb, hxT);
  ntrans_kernel<512, 16><<<4096, 256, 0, stream>>>(condA, statsc, gcw, gcb, h1T);
  wconv_kernel<<<1280, 256, 0, stream>>>(qw, kw, vw, wqh, wkh, wvh);
  proj_kernel<256, 0><<<1024, 256, 0, stream>>>(hxT, wqh, qb, Qh);
  proj_kernel<512, 1><<<1024, 256, 0, stream>>>(h1T, wkh, kb, Kh);
  proj_kernel<512, 2><<<1024, 256, 0, stream>>>(h1T, wvh, vb, Vh);
  attn_kernel<<<512, 256, 0, stream>>>(Qh, Kh, Vh, out);
}

// Round 4
// 590.176 us; speedup vs baseline: 1.3921x; 1.3921x over previous
//
#include <hip/hip_runtime.h>

// CrossAttentionSpatial: GN(x), GN(condA), Q/K/V 1x1 convs, 4096x4096 attention.
// B=8, C=256, E=512, N=M=4096, GROUPS=32.
//
// R4: same structure as R3 (32x32x16 MFMA attn; Q in regs; K staged to LDS in
// fragment order; V pre-tiled for direct coalesced global frag loads) but the
// cross-barrier register prefetch is REMOVED: R3's ds_write(kpre) followed by
// global_load overwriting kpre inside the same issue window is a WAR hazard
// that corrupts the K tile when L2 is warm (first launch correct, graph
// replays diverged). Now每 phase loads fresh: load->B0->LDS write->B1->
// S->P write->B2->PV. 3 barriers/iter, zero cross-barrier register reuse.

typedef _Float16 half8 __attribute__((ext_vector_type(8)));
typedef _Float16 half4v __attribute__((ext_vector_type(4)));
typedef float f32x4 __attribute__((ext_vector_type(4)));
typedef float f32x16 __attribute__((ext_vector_type(16)));

#define MFMA16(a, b, c) __builtin_amdgcn_mfma_f32_16x16x32_f16((a), (b), (c), 0, 0, 0)
#define MFMA32(a, b, c) __builtin_amdgcn_mfma_f32_32x32x16_f16((a), (b), (c), 0, 0, 0)

// ---------------------------------------------------------------------------
// Kernel 1: group stats (unchanged).
// ---------------------------------------------------------------------------
__global__ __launch_bounds__(256) void stats_kernel(
    const float* __restrict__ x, const float* __restrict__ condA,
    float* __restrict__ sx, float* __restrict__ sc) {
  int id = blockIdx.x;
  const float4* src;
  int nf4;
  float* dst;
  float inv_n;
  if (id < 256) {
    src = (const float4*)(x + (size_t)id * 32768);
    nf4 = 8192;
    dst = sx + id * 2;
    inv_n = 1.0f / 32768.0f;
  } else {
    int j = id - 256;
    src = (const float4*)(condA + (size_t)j * 65536);
    nf4 = 16384;
    dst = sc + j * 2;
    inv_n = 1.0f / 65536.0f;
  }
  int t = threadIdx.x;
  float s = 0.f, s2 = 0.f;
  for (int i = t; i < nf4; i += 256) {
    float4 v = src[i];
    s += v.x + v.y + v.z + v.w;
    s2 += v.x * v.x + v.y * v.y + v.z * v.z + v.w * v.w;
  }
#pragma unroll
  for (int m = 1; m <= 32; m <<= 1) {
    s += __shfl_xor(s, m, 64);
    s2 += __shfl_xor(s2, m, 64);
  }
  __shared__ float red[8];
  int w = t >> 6;
  if ((t & 63) == 0) { red[w * 2] = s; red[w * 2 + 1] = s2; }
  __syncthreads();
  if (t == 0) {
    float S = red[0] + red[2] + red[4] + red[6];
    float S2 = red[1] + red[3] + red[5] + red[7];
    float mu = S * inv_n;
    float var = S2 * inv_n - mu * mu;
    dst[0] = mu;
    dst[1] = rsqrtf(var + 1e-5f);
  }
}

// ---------------------------------------------------------------------------
// Kernel 2: normalize + transpose (unchanged).
// ---------------------------------------------------------------------------
template <int CH, int GS>
__global__ __launch_bounds__(256) void ntrans_kernel(
    const float* __restrict__ src, const float* __restrict__ stats,
    const float* __restrict__ gw, const float* __restrict__ gb,
    _Float16* __restrict__ dst) {
  int bid = blockIdx.x;
  int b = bid & 7, nt = (bid >> 3) & 63, ctile = bid >> 9;
  int n0 = nt * 64, c0 = ctile * 64;
  int t = threadIdx.x;
  __shared__ float tile[64][65];

  int cl = t >> 2;
  int c = c0 + cl;
  const float* st = stats + ((size_t)b * 32 + (c / GS)) * 2;
  float mu = st[0], rs = st[1];
  float a = rs * gw[c];
  float bb = gb[c] - mu * a;
  const float* srow = src + ((size_t)(b * CH + c)) * 4096 + n0 + (t & 3) * 16;
#pragma unroll
  for (int i = 0; i < 4; i++) {
    float4 v = *(const float4*)(srow + 4 * i);
    int nn = (t & 3) * 16 + 4 * i;
    tile[cl][nn + 0] = v.x * a + bb;
    tile[cl][nn + 1] = v.y * a + bb;
    tile[cl][nn + 2] = v.z * a + bb;
    tile[cl][nn + 3] = v.w * a + bb;
  }
  __syncthreads();
  int nl = t >> 2;
  half8 o0v, o1v;
#pragma unroll
  for (int i = 0; i < 8; i++) o0v[i] = (_Float16)tile[(t & 3) * 16 + i][nl];
#pragma unroll
  for (int i = 0; i < 8; i++) o1v[i] = (_Float16)tile[(t & 3) * 16 + 8 + i][nl];
  _Float16* drow = dst + ((size_t)b * 4096 + n0 + nl) * CH + c0 + (t & 3) * 16;
  *(half8*)drow = o0v;
  *((half8*)drow + 1) = o1v;
}

// ---------------------------------------------------------------------------
// Kernel 3: weight fp32 -> fp16 (unchanged).
// ---------------------------------------------------------------------------
__global__ __launch_bounds__(256) void wconv_kernel(
    const float* __restrict__ wq, const float* __restrict__ wk,
    const float* __restrict__ wv, _Float16* __restrict__ dq,
    _Float16* __restrict__ dk, _Float16* __restrict__ dv) {
  int i = blockIdx.x * 256 + threadIdx.x;
  if (i < 65536) dq[i] = (_Float16)wq[i];
  int j = i - 65536;
  if (j >= 0 && j < 131072) dk[j] = (_Float16)wk[j];
  int k = i - 196608;
  if (k >= 0 && k < 131072) dv[k] = (_Float16)wv[k];
}

// ---------------------------------------------------------------------------
// Kernel 4a: Q/K projection, W as A-operand -> vector 8B row-major stores
// (unchanged from R3; verified correct).
// ---------------------------------------------------------------------------
template <int CIN, int SCALE>
__global__ __launch_bounds__(256, 2) void projT_kernel(
    const _Float16* __restrict__ A, const _Float16* __restrict__ W,
    const float* __restrict__ bias, _Float16* __restrict__ out) {
  int bid = blockIdx.x;
  int b = bid & 7, nt = (bid >> 3) & 31, ot = bid >> 8;
  int n0 = nt * 128, o0 = ot * 64;
  int t = threadIdx.x, l = t & 63, w = t >> 6;
  int c15 = l & 15, q = l >> 4;

  const half8* aptr = (const half8*)(W + (size_t)(o0 + w * 16 + c15) * CIN) + q;
  const half8* bptr[8];
#pragma unroll
  for (int ct = 0; ct < 8; ct++)
    bptr[ct] = (const half8*)(A + ((size_t)b * 4096 + n0 + ct * 16 + c15) * CIN) + q;

  f32x4 acc[8] = {};
#pragma unroll 4
  for (int ks = 0; ks < CIN / 32; ks++) {
    half8 af = aptr[ks * 4];
#pragma unroll
    for (int ct = 0; ct < 8; ct++) acc[ct] = MFMA16(af, bptr[ct][ks * 4], acc[ct]);
  }
  int o4 = o0 + w * 16 + 4 * q;
  f32x4 bv = *(const f32x4*)(bias + o4);
#pragma unroll
  for (int ct = 0; ct < 8; ct++) {
    int n = n0 + ct * 16 + c15;
    half4v hv;
#pragma unroll
    for (int r = 0; r < 4; r++) {
      float v = acc[ct][r] + bv[r];
      if (SCALE) v *= 0.0625f;  // 1/sqrt(C) folded into Q
      hv[r] = (_Float16)v;
    }
    *(half4v*)(out + ((size_t)b * 4096 + n) * 256 + o4) = hv;
  }
}

// ---------------------------------------------------------------------------
// Kernel 4b: V projection -> 32x32x16 B-fragment tiled order (unchanged from
// R3; write-address bijection verified).
// ---------------------------------------------------------------------------
__global__ __launch_bounds__(256, 2) void projV_kernel(
    const _Float16* __restrict__ A, const _Float16* __restrict__ W,
    const float* __restrict__ bias, _Float16* __restrict__ Vt) {
  int bid = blockIdx.x;
  int b = bid & 7, nt = (bid >> 3) & 63, ot = bid >> 9;
  int n0 = nt * 64, o0 = ot * 128;
  int t = threadIdx.x, l = t & 63, w = t >> 6;
  int c15 = l & 15, q = l >> 4;
  int row = n0 + w * 16 + c15;

  const half8* arow = (const half8*)(A + ((size_t)b * 4096 + row) * 512) + q;
  const half8* wrows[8];
#pragma unroll
  for (int ct = 0; ct < 8; ct++)
    wrows[ct] = (const half8*)(W + (size_t)(o0 + ct * 16 + c15) * 512) + q;

  f32x4 acc[8] = {};
#pragma unroll 4
  for (int ks = 0; ks < 16; ks++) {
    half8 af = arow[ks * 4];
#pragma unroll
    for (int ct = 0; ct < 8; ct++) acc[ct] = MFMA16(af, wrows[ct][ks * 4], acc[ct]);
  }
  int m = n0 + w * 16 + 4 * q;
  size_t mbase = ((size_t)b * 256 + (m >> 4)) * 8;
#pragma unroll
  for (int ct = 0; ct < 8; ct++) {
    int c = o0 + ct * 16 + c15;
    float bs = bias[c];
    half4v pv4;
#pragma unroll
    for (int r = 0; r < 4; r++) pv4[r] = (_Float16)(acc[ct][r] + bs);
    size_t addr = ((mbase + (c >> 5)) * 64 + (c & 31) + ((q >> 1) << 5)) * 8 + (q & 1) * 4;
    *(half4v*)(Vt + addr) = pv4;
  }
}

// ---------------------------------------------------------------------------
// Kernel 5 (R4): flash attention, 32x32x16 MFMA, phase-local memory only.
// Per iter: load K tile to regs -> B0 -> write LDS (frag order, swizzled) ->
// B1 -> S-phase (16 MFMA) -> exp/P write (single 8KB buffer) -> B2 ->
// PV-phase (pf from LDS, vf fresh coalesced global loads from tiled Vt).
// No register is overwritten while a DS instruction reading it can be in
// flight (barrier drains lgkmcnt between write and next load).
// ---------------------------------------------------------------------------
__global__ __launch_bounds__(256, 2) void attn_kernel(
    const _Float16* __restrict__ Q, const _Float16* __restrict__ K,
    const _Float16* __restrict__ Vt, float* __restrict__ out) {
  int bid = blockIdx.x;
  int b = bid & 7, nt = bid >> 3;
  int n0 = nt * 64;
  int t = threadIdx.x, l = t & 63, w = t >> 6;
  int l31 = l & 31, h = l >> 5;
  int mh = w & 1, nh = w >> 1;

  __shared__ __align__(16) _Float16 kf_lds[16384];  // K tile, frag order, 32KB
  __shared__ __align__(16) _Float16 p_lds[4096];    // P, frag order, 8KB
  __shared__ __align__(16) float lsw[2][64];

  // Q B-frags: n = n0 + nh*32 + l31, k-chunk = ks*16 + h*8
  half8 qf[16];
  {
    const _Float16* qb = Q + ((size_t)(b * 4096 + n0 + nh * 32 + l31)) * 256 + h * 8;
#pragma unroll
    for (int ks = 0; ks < 16; ks++) qf[ks] = *(const half8*)(qb + ks * 16);
  }

  // K staging: thread t covers row km = t>>2, 16B chunks ch = (t&3) + 4i.
  // LDS frag slot: [(km>>5)*16 + kblk][lanep ^ (kblk&7)], kblk = ch>>1,
  // lanep = (km&31) + 32*(ch&1).
  int km = t >> 2, kc = t & 3;
  const half8* kgl = (const half8*)(K + ((size_t)b * 4096 + km) * 256) + kc;
  int kw_addr[8];
#pragma unroll
  for (int i = 0; i < 8; i++) {
    int ch = kc + 4 * i;
    int kblk = ch >> 1;
    int lanep = (km & 31) + ((ch & 1) << 5);
    kw_addr[i] = (((km >> 5) * 16 + kblk) * 64 + (lanep ^ (kblk & 7))) * 8;
  }

  const half8* vt8 = (const half8*)Vt + (size_t)b * 256 * 8 * 64;

  f32x16 acc_o[4] = {};
  float l_part = 0.f;

  for (int it = 0; it < 64; it++) {
    // ---- load K tile fresh (RAW-only), stage to LDS ----
    half8 kreg[8];
#pragma unroll
    for (int i = 0; i < 8; i++) kreg[i] = kgl[it * 2048 + 4 * i];
    __syncthreads();  // B0: prior S reads of kf_lds + PV reads of p_lds done
#pragma unroll
    for (int i = 0; i < 8; i++) *(half8*)&kf_lds[kw_addr[i]] = kreg[i];
    __syncthreads();  // B1: K visible

    // ---- S^T = K Q^T : wave tile [32m x 32n], 1 LDS b128 per MFMA ----
    f32x16 s = {};
#pragma unroll
    for (int ks = 0; ks < 16; ks++) {
      half8 kf = *(const half8*)&kf_lds[((mh * 16 + ks) * 64 + (l ^ (ks & 7))) * 8];
      s = MFMA32(kf, qf[ks], s);
    }

    // ---- P = exp(S^T), row-sum accumulate, write P in A-frag order ----
    // C-layout: col n = l31, row m_local = (reg&3) + 8*(reg>>2) + 4h.
#pragma unroll
    for (int k2 = 0; k2 < 4; k2++) {
      half4v pv;
#pragma unroll
      for (int r = 0; r < 4; r++) {
        float e = __expf(s[4 * k2 + r]);
        l_part += e;
        pv[r] = (_Float16)e;
      }
      *(half4v*)&p_lds[((nh * 4 + mh * 2 + (k2 >> 1)) * 64 + l31 + ((k2 & 1) << 5)) * 8 + 4 * h] = pv;
    }
    __syncthreads();  // B2: P visible

    // ---- O += P V : wave = 32n (nh) x 128c (mh), V direct from tiled global ----
#pragma unroll
    for (int ks = 0; ks < 4; ks++) {
      half8 pf = *(const half8*)&p_lds[((nh * 4 + ks) * 64 + l) * 8];
      half8 vf[4];
#pragma unroll
      for (int ct = 0; ct < 4; ct++)
        vf[ct] = vt8[((size_t)(it * 4 + ks) * 8 + (mh * 4 + ct)) * 64 + l];
#pragma unroll
      for (int ct = 0; ct < 4; ct++) acc_o[ct] = MFMA32(pf, vf[ct], acc_o[ct]);
    }
  }

  // ---- epilogue: combine l over h-pairs and the 2 mh waves; normalize ----
  {
    float v = l_part + __shfl_xor(l_part, 32, 64);
    if (l < 32) lsw[mh][nh * 32 + l] = v;
  }
  __syncthreads();
#pragma unroll
  for (int k2 = 0; k2 < 4; k2++) {
    int nb = nh * 32 + 4 * h + 8 * k2;
    f32x4 s0 = *(const f32x4*)&lsw[0][nb];
    f32x4 s1 = *(const f32x4*)&lsw[1][nb];
    f32x4 linv;
#pragma unroll
    for (int r = 0; r < 4; r++) linv[r] = 1.0f / (s0[r] + s1[r]);
#pragma unroll
    for (int ct = 0; ct < 4; ct++) {
      int c = mh * 128 + ct * 32 + l31;
      f32x4 o4;
#pragma unroll
      for (int r = 0; r < 4; r++) o4[r] = acc_o[ct][4 * k2 + r] * linv[r];
      *(f32x4*)(out + ((size_t)(b * 256 + c)) * 4096 + n0 + nb) = o4;
    }
  }
}

// ---------------------------------------------------------------------------
extern "C" void kernel_launch(void* const* d_in, const int* in_sizes, int n_in,
                              void* d_out, int out_size, void* d_ws,
                              size_t ws_size, hipStream_t stream) {
  const float* x = (const float*)d_in[0];
  const float* condA = (const float*)d_in[1];
  const float* gxw = (const float*)d_in[2];
  const float* gxb = (const float*)d_in[3];
  const float* gcw = (const float*)d_in[4];
  const float* gcb = (const float*)d_in[5];
  const float* qw = (const float*)d_in[6];
  const float* qb = (const float*)d_in[7];
  const float* kw = (const float*)d_in[8];
  const float* kb = (const float*)d_in[9];
  const float* vw = (const float*)d_in[10];
  const float* vb = (const float*)d_in[11];
  float* out = (float*)d_out;

  char* ws = (char*)d_ws;
  float* statsx = (float*)(ws);                     // 2048 B
  float* statsc = (float*)(ws + 2048);              // 2048 B
  _Float16* wqh = (_Float16*)(ws + 4096);           // 128 KB
  _Float16* wkh = (_Float16*)(ws + 135168);         // 256 KB
  _Float16* wvh = (_Float16*)(ws + 397312);         // 256 KB
  char* p = ws + 659456;
  _Float16* hxT = (_Float16*)p; p += (size_t)8 * 4096 * 256 * 2;  // 16 MB
  _Float16* h1T = (_Float16*)p; p += (size_t)8 * 4096 * 512 * 2;  // 32 MB
  _Float16* Qh = (_Float16*)p;  p += (size_t)8 * 4096 * 256 * 2;  // 16 MB
  _Float16* Kh = (_Float16*)p;  p += (size_t)8 * 4096 * 256 * 2;  // 16 MB
  _Float16* Vt = (_Float16*)p;                                    // 16 MB (tiled)

  stats_kernel<<<512, 256, 0, stream>>>(x, condA, statsx, statsc);
  ntrans_kernel<256, 8><<<2048, 256, 0, stream>>>(x, statsx, gxw, gxb, hxT);
  ntrans_kernel<512, 16><<<4096, 256, 0, stream>>>(condA, statsc, gcw, gcb, h1T);
  wconv_kernel<<<1280, 256, 0, stream>>>(qw, kw, vw, wqh, wkh, wvh);
  projT_kernel<256, 1><<<1024, 256, 0, stream>>>(hxT, wqh, qb, Qh);
  projT_kernel<512, 0><<<1024, 256, 0, stream>>>(h1T, wkh, kb, Kh);
  projV_kernel<<<1024, 256, 0, stream>>>(h1T, wvh, vb, Vt);
  attn_kernel<<<512, 256, 0, stream>>>(Qh, Kh, Vt, out);
}

// Round 5
// 441.218 us; speedup vs baseline: 1.8620x; 1.3376x over previous
//
#include <hip/hip_runtime.h>

// CrossAttentionSpatial: GN(x), GN(condA), Q/K/V 1x1 convs, 4096x4096 attention.
// B=8, C=256, E=512, N=M=4096, GROUPS=32.
//
// R5: (a) attn software-pipelined: K(i+1)/V(i) global loads issued at S-phase
// start (~400cy cover), ds_write after B0, register reload only after B1's
// lgkmcnt(0) drain (R3's WAR hazard structurally impossible). 2 barriers/iter.
// (b) conflict-free LDS addressing: granule(m,h)=((m^h)|(h<<5))^((kblk&3)<<1)
// puts h in bit0 / kblk in bits1-2 / m in low bits -> every 8-lane group of
// every LDS access hits 8 distinct bank-quads. K staging is coalesced 1KB
// wave-loads. (c) projections take BOTH operands in MFMA-frag tile order
// (produced by ntrans/wconv) -> all proj loads are base+lane*16B contiguous.

typedef _Float16 half8 __attribute__((ext_vector_type(8)));
typedef _Float16 half4v __attribute__((ext_vector_type(4)));
typedef float f32x4 __attribute__((ext_vector_type(4)));
typedef float f32x16 __attribute__((ext_vector_type(16)));

#define MFMA16(a, b, c) __builtin_amdgcn_mfma_f32_16x16x32_f16((a), (b), (c), 0, 0, 0)
#define MFMA32(a, b, c) __builtin_amdgcn_mfma_f32_32x32x16_f16((a), (b), (c), 0, 0, 0)

// ---------------------------------------------------------------------------
// Kernel 1: group stats (unchanged).
// ---------------------------------------------------------------------------
__global__ __launch_bounds__(256) void stats_kernel(
    const float* __restrict__ x, const float* __restrict__ condA,
    float* __restrict__ sx, float* __restrict__ sc) {
  int id = blockIdx.x;
  const float4* src;
  int nf4;
  float* dst;
  float inv_n;
  if (id < 256) {
    src = (const float4*)(x + (size_t)id * 32768);
    nf4 = 8192;
    dst = sx + id * 2;
    inv_n = 1.0f / 32768.0f;
  } else {
    int j = id - 256;
    src = (const float4*)(condA + (size_t)j * 65536);
    nf4 = 16384;
    dst = sc + j * 2;
    inv_n = 1.0f / 65536.0f;
  }
  int t = threadIdx.x;
  float s = 0.f, s2 = 0.f;
  for (int i = t; i < nf4; i += 256) {
    float4 v = src[i];
    s += v.x + v.y + v.z + v.w;
    s2 += v.x * v.x + v.y * v.y + v.z * v.z + v.w * v.w;
  }
#pragma unroll
  for (int m = 1; m <= 32; m <<= 1) {
    s += __shfl_xor(s, m, 64);
    s2 += __shfl_xor(s2, m, 64);
  }
  __shared__ float red[8];
  int w = t >> 6;
  if ((t & 63) == 0) { red[w * 2] = s; red[w * 2 + 1] = s2; }
  __syncthreads();
  if (t == 0) {
    float S = red[0] + red[2] + red[4] + red[6];
    float S2 = red[1] + red[3] + red[5] + red[7];
    float mu = S * inv_n;
    float var = S2 * inv_n - mu * mu;
    dst[0] = mu;
    dst[1] = rsqrtf(var + 1e-5f);
  }
}

// ---------------------------------------------------------------------------
// Kernel 2: normalize + transpose -> FRAG-TILED fp16 activations.
// dst layout: [b][n>>4][CH/32 ks][64 granule][8], granule = (n&15) + 16*q
// where q = (c>>3)&3 -> a 16x16x32 A/B-frag load is base + lane*16B.
// ---------------------------------------------------------------------------
template <int CH, int GS>
__global__ __launch_bounds__(256) void ntrans_kernel(
    const float* __restrict__ src, const float* __restrict__ stats,
    const float* __restrict__ gw, const float* __restrict__ gb,
    _Float16* __restrict__ dst) {
  int bid = blockIdx.x;
  int b = bid & 7, nt = (bid >> 3) & 63, ctile = bid >> 9;
  int n0 = nt * 64, c0 = ctile * 64;
  int t = threadIdx.x;
  __shared__ float tile[64][65];

  int cl = t >> 2;
  int c = c0 + cl;
  const float* st = stats + ((size_t)b * 32 + (c / GS)) * 2;
  float mu = st[0], rs = st[1];
  float a = rs * gw[c];
  float bb = gb[c] - mu * a;
  const float* srow = src + ((size_t)(b * CH + c)) * 4096 + n0 + (t & 3) * 16;
#pragma unroll
  for (int i = 0; i < 4; i++) {
    float4 v = *(const float4*)(srow + 4 * i);
    int nn = (t & 3) * 16 + 4 * i;
    tile[cl][nn + 0] = v.x * a + bb;
    tile[cl][nn + 1] = v.y * a + bb;
    tile[cl][nn + 2] = v.z * a + bb;
    tile[cl][nn + 3] = v.w * a + bb;
  }
  __syncthreads();
  int nl = t >> 2;
  half8 ov[2];
#pragma unroll
  for (int u = 0; u < 2; u++)
#pragma unroll
    for (int i = 0; i < 8; i++) ov[u][i] = (_Float16)tile[(t & 3) * 16 + 8 * u + i][nl];
  int n = n0 + nl;
  size_t tb = ((size_t)b * 256 + (n >> 4)) * (CH / 32);
  int ca = c0 + (t & 3) * 16;
#pragma unroll
  for (int u = 0; u < 2; u++) {
    int cc = ca + 8 * u;
    size_t addr = ((tb + (cc >> 5)) * 64 + (n & 15) + 16 * ((cc >> 3) & 3)) * 8;
    *(half8*)(dst + addr) = ov[u];
  }
}

// ---------------------------------------------------------------------------
// Kernel 3: weights fp32 -> fp16 FRAG-TILED. Wt layout: [o>>4][CIN/32 ks]
// [64 granule][8], granule = (o&15) + 16*((k>>3)&3). One granule per thread.
// ---------------------------------------------------------------------------
__global__ __launch_bounds__(256) void wconv_kernel(
    const float* __restrict__ wq, const float* __restrict__ wk,
    const float* __restrict__ wv, _Float16* __restrict__ wqt,
    _Float16* __restrict__ wkt, _Float16* __restrict__ wvt) {
  int i = blockIdx.x * 256 + threadIdx.x;
  const float* src;
  _Float16* dst;
  int cin, ksbits, gi;
  if (i < 8192) { src = wq; dst = wqt; cin = 256; ksbits = 3; gi = i; }
  else if (i < 24576) { src = wk; dst = wkt; cin = 512; ksbits = 4; gi = i - 8192; }
  else if (i < 40960) { src = wv; dst = wvt; cin = 512; ksbits = 4; gi = i - 24576; }
  else return;
  int tile = gi >> 6, g = gi & 63;
  int otile = tile >> ksbits, ks = tile & ((1 << ksbits) - 1);
  int o = otile * 16 + (g & 15), k = ks * 32 + (g >> 4) * 8;
  const float* s = src + (size_t)o * cin + k;
  half8 hv;
#pragma unroll
  for (int j = 0; j < 8; j++) hv[j] = (_Float16)s[j];
  *(half8*)(dst + (size_t)gi * 8) = hv;
}

// ---------------------------------------------------------------------------
// Kernel 4a: Q/K projection, tiled operands. A-frag = Wt (o rows), B-frag =
// Ht (n cols); every load = base + lane*16B. Wave: 16 o x 128 n. Block 64 o
// x 128 n. C-layout -> 4 consecutive o per lane -> 8B row-major stores
// (epilogue identical to R3-verified projT). Grid 8*32*4 = 1024.
// ---------------------------------------------------------------------------
template <int CIN, int SCALE>
__global__ __launch_bounds__(256, 2) void projQK_kernel(
    const _Float16* __restrict__ Ht, const _Float16* __restrict__ Wt,
    const float* __restrict__ bias, _Float16* __restrict__ out) {
  int bid = blockIdx.x;
  int b = bid & 7, nt = (bid >> 3) & 31, ot = bid >> 8;
  int n0 = nt * 128, o0 = ot * 64;
  int t = threadIdx.x, l = t & 63, w = t >> 6;
  int c15 = l & 15, q = l >> 4;
  constexpr int KS = CIN / 32;

  const half8* ap = (const half8*)Wt + ((size_t)(ot * 4 + w) * KS) * 64 + l;
  const half8* bp = (const half8*)Ht + ((size_t)(b * 256 + nt * 8) * KS) * 64 + l;

  f32x4 acc[8] = {};
#pragma unroll
  for (int ks = 0; ks < KS; ks++) {
    half8 af = ap[ks * 64];
#pragma unroll
    for (int ct = 0; ct < 8; ct++)
      acc[ct] = MFMA16(af, bp[(ct * KS + ks) * 64], acc[ct]);
  }
  int o4 = o0 + w * 16 + 4 * q;
  f32x4 bv = *(const f32x4*)(bias + o4);
#pragma unroll
  for (int ct = 0; ct < 8; ct++) {
    int n = n0 + ct * 16 + c15;
    half4v hv;
#pragma unroll
    for (int r = 0; r < 4; r++) {
      float v = acc[ct][r] + bv[r];
      if (SCALE) v *= 0.0625f;  // 1/sqrt(C) folded into Q
      hv[r] = (_Float16)v;
    }
    *(half4v*)(out + ((size_t)b * 4096 + n) * 256 + o4) = hv;
  }
}

// ---------------------------------------------------------------------------
// Kernel 4b: V projection, tiled operands. A-frag = h1Tt (m rows), B-frag =
// Wvt (c cols). Epilogue = R3-verified Vt scatter (32x32 B-frag tiled order
// for attn PV). Wave: 16 m x 128 c. Grid 8*64*2 = 1024.
// ---------------------------------------------------------------------------
__global__ __launch_bounds__(256, 2) void projV_kernel(
    const _Float16* __restrict__ Ht, const _Float16* __restrict__ Wt,
    const float* __restrict__ bias, _Float16* __restrict__ Vt) {
  int bid = blockIdx.x;
  int b = bid & 7, mt = (bid >> 3) & 63, ct2 = bid >> 9;
  int m0 = mt * 64, c0 = ct2 * 128;
  int t = threadIdx.x, l = t & 63, w = t >> 6;
  int c15 = l & 15, q = l >> 4;
  constexpr int KS = 16;

  const half8* ap = (const half8*)Ht + ((size_t)(b * 256 + mt * 4 + w) * KS) * 64 + l;
  const half8* bp = (const half8*)Wt + ((size_t)(c0 >> 4) * KS) * 64 + l;

  f32x4 acc[8] = {};
#pragma unroll
  for (int ks = 0; ks < KS; ks++) {
    half8 af = ap[ks * 64];
#pragma unroll
    for (int ct = 0; ct < 8; ct++)
      acc[ct] = MFMA16(af, bp[(ct * KS + ks) * 64], acc[ct]);
  }
  int m = m0 + w * 16 + 4 * q;
  size_t mbase = ((size_t)b * 256 + (m >> 4)) * 8;
#pragma unroll
  for (int ct = 0; ct < 8; ct++) {
    int c = c0 + ct * 16 + c15;
    float bs = bias[c];
    half4v pv4;
#pragma unroll
    for (int r = 0; r < 4; r++) pv4[r] = (_Float16)(acc[ct][r] + bs);
    size_t addr = ((mbase + (c >> 5)) * 64 + (c & 31) + ((q >> 1) << 5)) * 8 + (q & 1) * 4;
    *(half4v*)(Vt + addr) = pv4;
  }
}

// ---------------------------------------------------------------------------
// Kernel 5 (R5): pipelined flash attention, 32x32x16 MFMA.
// K LDS layout: tile (mblk*16+kblk)*512 halfs, granule(m5,h) =
// ((m5^h)|(h<<5)) ^ ((kblk&3)<<1)  -> h bit0, kblk bits1-2, m low bits:
// conflict-free for both coalesced staging writes and frag reads.
// P LDS: tile (nblk*4+km)*512, granule(n5,hm) = (n5^hm)|(hm<<5).
// Pipeline/iter: [prefetch K(i+1),V(i) | S-phase | exp | B0 | write P,K | B1
// | prefetch V hi | PV]. Register WAR on kreg crosses B1 (lgkm drained).
// ---------------------------------------------------------------------------
__global__ __launch_bounds__(256, 2) void attn_kernel(
    const _Float16* __restrict__ Q, const _Float16* __restrict__ K,
    const _Float16* __restrict__ Vt, float* __restrict__ out) {
  int bid = blockIdx.x;
  int b = bid & 7, nt = bid >> 3;
  int n0 = nt * 64;
  int t = threadIdx.x, l = t & 63, w = t >> 6;
  int l31 = l & 31, h = l >> 5;
  int mh = w & 1, nh = w >> 1;

  __shared__ __align__(16) _Float16 kbuf[16384];  // 32KB K tile, frag+swizzle
  __shared__ __align__(16) _Float16 pbuf[4096];   // 8KB P, frag order
  __shared__ float lsw[2][64];

  // Q B-frags (row-major; one-time load amortized over 64 iters)
  half8 qf[16];
  {
    const _Float16* qb = Q + ((size_t)(b * 4096 + n0 + nh * 32 + l31)) * 256 + h * 8;
#pragma unroll
    for (int ks = 0; ks < 16; ks++) qf[ks] = *(const half8*)(qb + ks * 16);
  }

  // K staging: thread (w,l) covers rows m_i = w*16 + 2i + h, chunk ch = l31.
  // Global: fully coalesced 1KB per wave-instr (2 adjacent rows).
  const half8* kgl = (const half8*)(K + ((size_t)b * 4096 + w * 16 + h) * 256) + l31;
  int kwa[8];
  {
    int kblk = l31 >> 1, hw = l & 1;
    int swz = (kblk & 3) << 1;
    int mblk = w >> 1;
#pragma unroll
    for (int i = 0; i < 8; i++) {
      int m5 = ((w & 1) << 4) + 2 * i + h;
      int g = ((m5 ^ hw) | (hw << 5)) ^ swz;
      kwa[i] = (mblk * 16 + kblk) * 512 + g * 8;
    }
  }
  int gbase = (l31 ^ h) | (h << 5);

  const half8* vt8 = (const half8*)Vt + (size_t)b * 256 * 8 * 64;

  f32x16 acc_o[4] = {};
  float l_part = 0.f;

  // preload tile 0
  half8 kreg[8];
#pragma unroll
  for (int i = 0; i < 8; i++) kreg[i] = kgl[i * 64];
#pragma unroll
  for (int i = 0; i < 8; i++) *(half8*)&kbuf[kwa[i]] = kreg[i];
  __syncthreads();

  for (int it = 0; it < 64; it++) {
    int itn = it < 63 ? it + 1 : 63;
    // prefetch K(it+1): kreg last ds_written before B1 of prev iter (drained)
#pragma unroll
    for (int i = 0; i < 8; i++) kreg[i] = kgl[itn * 2048 + i * 64];
    // prefetch V frags ks=0,1
    half8 vf0[8];
#pragma unroll
    for (int u = 0; u < 2; u++)
#pragma unroll
      for (int ct = 0; ct < 4; ct++)
        vf0[u * 4 + ct] = vt8[((size_t)(it * 4 + u) * 8 + (mh * 4 + ct)) * 64 + l];

    // ---- S^T = K Q^T : wave [32m x 32n], conflict-free frag reads ----
    f32x16 s = {};
#pragma unroll
    for (int ks = 0; ks < 16; ks++) {
      half8 kf = *(const half8*)&kbuf[(mh * 16 + ks) * 512 + (gbase ^ ((ks & 3) << 1)) * 8];
      s = MFMA32(kf, qf[ks], s);
    }

    // ---- exp + row-sum ----
    half4v pv[4];
#pragma unroll
    for (int k2 = 0; k2 < 4; k2++) {
#pragma unroll
      for (int r = 0; r < 4; r++) {
        float e = __expf(s[4 * k2 + r]);
        l_part += e;
        pv[k2][r] = (_Float16)e;
      }
    }
    __syncthreads();  // B0: kbuf S-reads + pbuf PV-reads (prev) complete

    // ---- write P (C-layout -> frag order) and K(it+1) ----
#pragma unroll
    for (int k2 = 0; k2 < 4; k2++) {
      int hm = k2 & 1;
      int tau = nh * 4 + mh * 2 + (k2 >> 1);
      int g = (l31 ^ hm) | (hm << 5);
      *(half4v*)&pbuf[tau * 512 + g * 8 + 4 * h] = pv[k2];
    }
#pragma unroll
    for (int i = 0; i < 8; i++) *(half8*)&kbuf[kwa[i]] = kreg[i];
    __syncthreads();  // B1: P(it) + K(it+1) visible; lgkm drained (WAR-safe)

    // ---- O += P V : P from LDS (conflict-free), V direct tiled global ----
    half8 vf1[8];
#pragma unroll
    for (int u = 0; u < 2; u++)
#pragma unroll
      for (int ct = 0; ct < 4; ct++)
        vf1[u * 4 + ct] = vt8[((size_t)(it * 4 + 2 + u) * 8 + (mh * 4 + ct)) * 64 + l];
#pragma unroll
    for (int ks = 0; ks < 2; ks++) {
      half8 pf = *(const half8*)&pbuf[(nh * 4 + ks) * 512 + gbase * 8];
#pragma unroll
      for (int ct = 0; ct < 4; ct++) acc_o[ct] = MFMA32(pf, vf0[ks * 4 + ct], acc_o[ct]);
    }
#pragma unroll
    for (int ks = 2; ks < 4; ks++) {
      half8 pf = *(const half8*)&pbuf[(nh * 4 + ks) * 512 + gbase * 8];
#pragma unroll
      for (int ct = 0; ct < 4; ct++) acc_o[ct] = MFMA32(pf, vf1[(ks - 2) * 4 + ct], acc_o[ct]);
    }
  }

  // ---- epilogue: combine l over h-pairs and the 2 mh waves; normalize ----
  {
    float v = l_part + __shfl_xor(l_part, 32, 64);
    if (l < 32) lsw[mh][nh * 32 + l] = v;
  }
  __syncthreads();
#pragma unroll
  for (int k2 = 0; k2 < 4; k2++) {
    int nb = nh * 32 + 4 * h + 8 * k2;
    f32x4 s0 = *(const f32x4*)&lsw[0][nb];
    f32x4 s1 = *(const f32x4*)&lsw[1][nb];
    f32x4 linv;
#pragma unroll
    for (int r = 0; r < 4; r++) linv[r] = 1.0f / (s0[r] + s1[r]);
#pragma unroll
    for (int ct = 0; ct < 4; ct++) {
      int c = mh * 128 + ct * 32 + l31;
      f32x4 o4;
#pragma unroll
      for (int r = 0; r < 4; r++) o4[r] = acc_o[ct][4 * k2 + r] * linv[r];
      *(f32x4*)(out + ((size_t)(b * 256 + c)) * 4096 + n0 + nb) = o4;
    }
  }
}

// ---------------------------------------------------------------------------
extern "C" void kernel_launch(void* const* d_in, const int* in_sizes, int n_in,
                              void* d_out, int out_size, void* d_ws,
                              size_t ws_size, hipStream_t stream) {
  const float* x = (const float*)d_in[0];
  const float* condA = (const float*)d_in[1];
  const float* gxw = (const float*)d_in[2];
  const float* gxb = (const float*)d_in[3];
  const float* gcw = (const float*)d_in[4];
  const float* gcb = (const float*)d_in[5];
  const float* qw = (const float*)d_in[6];
  const float* qb = (const float*)d_in[7];
  const float* kw = (const float*)d_in[8];
  const float* kb = (const float*)d_in[9];
  const float* vw = (const float*)d_in[10];
  const float* vb = (const float*)d_in[11];
  float* out = (float*)d_out;

  char* ws = (char*)d_ws;
  float* statsx = (float*)(ws);                     // 2048 B
  float* statsc = (float*)(ws + 2048);              // 2048 B
  _Float16* wqt = (_Float16*)(ws + 4096);           // 128 KB (tiled)
  _Float16* wkt = (_Float16*)(ws + 135168);         // 256 KB (tiled)
  _Float16* wvt = (_Float16*)(ws + 397312);         // 256 KB (tiled)
  char* p = ws + 659456;
  _Float16* hxTt = (_Float16*)p; p += (size_t)8 * 4096 * 256 * 2;  // 16 MB tiled
  _Float16* h1Tt = (_Float16*)p; p += (size_t)8 * 4096 * 512 * 2;  // 32 MB tiled
  _Float16* Qh = (_Float16*)p;   p += (size_t)8 * 4096 * 256 * 2;  // 16 MB row-major
  _Float16* Kh = (_Float16*)p;   p += (size_t)8 * 4096 * 256 * 2;  // 16 MB row-major
  _Float16* Vt = (_Float16*)p;                                     // 16 MB tiled

  stats_kernel<<<512, 256, 0, stream>>>(x, condA, statsx, statsc);
  ntrans_kernel<256, 8><<<2048, 256, 0, stream>>>(x, statsx, gxw, gxb, hxTt);
  ntrans_kernel<512, 16><<<4096, 256, 0, stream>>>(condA, statsc, gcw, gcb, h1Tt);
  wconv_kernel<<<160, 256, 0, stream>>>(qw, kw, vw, wqt, wkt, wvt);
  projQK_kernel<256, 1><<<1024, 256, 0, stream>>>(hxTt, wqt, qb, Qh);
  projQK_kernel<512, 0><<<1024, 256, 0, stream>>>(h1Tt, wkt, kb, Kh);
  projV_kernel<<<1024, 256, 0, stream>>>(h1Tt, wvt, vb, Vt);
  attn_kernel<<<512, 256, 0, stream>>>(Qh, Kh, Vt, out);
}

// Round 6
// 393.615 us; speedup vs baseline: 2.0872x; 1.1209x over previous
//
#include <hip/hip_runtime.h>

// CrossAttentionSpatial: GN(x), GN(condA), Q/K/V 1x1 convs, 4096x4096 attention.
// B=8, C=256, E=512, N=M=4096, GROUPS=32.
//
// R6: all attention operands pre-tiled in MFMA-frag order (Qt/Kt new, Vt as
// verified): attn K-staging becomes pure contiguous memcpy (no swizzle), Q
// frag loads contiguous 1KB. Projections stage their activation slice to LDS
// once (tiled global -> linear copy) and compute ALL outputs from it: projQ
// (256 o), projKV (K 256 o + V 256 c fused, each LDS frag feeds both a
// K-MFMA and a V-MFMA). Zero activation re-read from HBM. 5 launches total.

typedef _Float16 half8 __attribute__((ext_vector_type(8)));
typedef _Float16 half4v __attribute__((ext_vector_type(4)));
typedef float f32x4 __attribute__((ext_vector_type(4)));
typedef float f32x16 __attribute__((ext_vector_type(16)));

#define MFMA16(a, b, c) __builtin_amdgcn_mfma_f32_16x16x32_f16((a), (b), (c), 0, 0, 0)
#define MFMA32(a, b, c) __builtin_amdgcn_mfma_f32_32x32x16_f16((a), (b), (c), 0, 0, 0)

// ---------------------------------------------------------------------------
// Kernel 1: group stats (blocks 0..511) + weight fp32->fp16 frag-tiling
// (blocks 512..671). Wt layout: [o>>4][CIN/32 ks][64 g][8], g = (o&15) +
// 16*((k>>3)&3).
// ---------------------------------------------------------------------------
__global__ __launch_bounds__(256) void statswconv_kernel(
    const float* __restrict__ x, const float* __restrict__ condA,
    float* __restrict__ sx, float* __restrict__ sc,
    const float* __restrict__ wq, const float* __restrict__ wk,
    const float* __restrict__ wv, _Float16* __restrict__ wqt,
    _Float16* __restrict__ wkt, _Float16* __restrict__ wvt) {
  int bid = blockIdx.x;
  int t = threadIdx.x;
  if (bid >= 512) {
    int i = (bid - 512) * 256 + t;
    const float* src;
    _Float16* dst;
    int cin, ksbits, gi;
    if (i < 8192) { src = wq; dst = wqt; cin = 256; ksbits = 3; gi = i; }
    else if (i < 24576) { src = wk; dst = wkt; cin = 512; ksbits = 4; gi = i - 8192; }
    else { src = wv; dst = wvt; cin = 512; ksbits = 4; gi = i - 24576; }
    int tile = gi >> 6, g = gi & 63;
    int otile = tile >> ksbits, ks = tile & ((1 << ksbits) - 1);
    int o = otile * 16 + (g & 15), k = ks * 32 + (g >> 4) * 8;
    const float* s = src + (size_t)o * cin + k;
    half8 hv;
#pragma unroll
    for (int j = 0; j < 8; j++) hv[j] = (_Float16)s[j];
    *(half8*)(dst + (size_t)gi * 8) = hv;
    return;
  }
  const float4* src;
  int nf4;
  float* dst;
  float inv_n;
  if (bid < 256) {
    src = (const float4*)(x + (size_t)bid * 32768);
    nf4 = 8192;
    dst = sx + bid * 2;
    inv_n = 1.0f / 32768.0f;
  } else {
    int j = bid - 256;
    src = (const float4*)(condA + (size_t)j * 65536);
    nf4 = 16384;
    dst = sc + j * 2;
    inv_n = 1.0f / 65536.0f;
  }
  float s = 0.f, s2 = 0.f;
  for (int i = t; i < nf4; i += 256) {
    float4 v = src[i];
    s += v.x + v.y + v.z + v.w;
    s2 += v.x * v.x + v.y * v.y + v.z * v.z + v.w * v.w;
  }
#pragma unroll
  for (int m = 1; m <= 32; m <<= 1) {
    s += __shfl_xor(s, m, 64);
    s2 += __shfl_xor(s2, m, 64);
  }
  __shared__ float red[8];
  int w = t >> 6;
  if ((t & 63) == 0) { red[w * 2] = s; red[w * 2 + 1] = s2; }
  __syncthreads();
  if (t == 0) {
    float S = red[0] + red[2] + red[4] + red[6];
    float S2 = red[1] + red[3] + red[5] + red[7];
    float mu = S * inv_n;
    float var = S2 * inv_n - mu * mu;
    dst[0] = mu;
    dst[1] = rsqrtf(var + 1e-5f);
  }
}

// ---------------------------------------------------------------------------
// Kernel 2: normalize + transpose -> frag-tiled fp16 (both inputs, one
// launch). dst: [b][n>>4][CH/32 ks][64 g][8], g = (n&15) + 16*((c>>3)&3).
// Blocks 0..2047: x-path (CH=256); 2048..6143: condA (CH=512).
// ---------------------------------------------------------------------------
__global__ __launch_bounds__(256) void ntrans_kernel(
    const float* __restrict__ x, const float* __restrict__ condA,
    const float* __restrict__ statsx, const float* __restrict__ statsc,
    const float* __restrict__ gxw, const float* __restrict__ gxb,
    const float* __restrict__ gcw, const float* __restrict__ gcb,
    _Float16* __restrict__ hxTt, _Float16* __restrict__ h1Tt) {
  int bid = blockIdx.x;
  const float *src, *stats, *gw, *gb;
  _Float16* dst;
  int CH, gsh, bid2;
  if (bid < 2048) {
    src = x; stats = statsx; gw = gxw; gb = gxb; dst = hxTt;
    CH = 256; gsh = 3; bid2 = bid;
  } else {
    src = condA; stats = statsc; gw = gcw; gb = gcb; dst = h1Tt;
    CH = 512; gsh = 4; bid2 = bid - 2048;
  }
  int b = bid2 & 7, nt = (bid2 >> 3) & 63, ctile = bid2 >> 9;
  int n0 = nt * 64, c0 = ctile * 64;
  int t = threadIdx.x;
  __shared__ float tile[64][65];

  int cl = t >> 2;
  int c = c0 + cl;
  const float* st = stats + ((size_t)b * 32 + (c >> gsh)) * 2;
  float mu = st[0], rs = st[1];
  float a = rs * gw[c];
  float bb = gb[c] - mu * a;
  const float* srow = src + ((size_t)(b * CH + c)) * 4096 + n0 + (t & 3) * 16;
#pragma unroll
  for (int i = 0; i < 4; i++) {
    float4 v = *(const float4*)(srow + 4 * i);
    int nn = (t & 3) * 16 + 4 * i;
    tile[cl][nn + 0] = v.x * a + bb;
    tile[cl][nn + 1] = v.y * a + bb;
    tile[cl][nn + 2] = v.z * a + bb;
    tile[cl][nn + 3] = v.w * a + bb;
  }
  __syncthreads();
  int nl = t >> 2;
  half8 ov[2];
#pragma unroll
  for (int u = 0; u < 2; u++)
#pragma unroll
    for (int i = 0; i < 8; i++) ov[u][i] = (_Float16)tile[(t & 3) * 16 + 8 * u + i][nl];
  int n = n0 + nl;
  size_t tb = ((size_t)b * 256 + (n >> 4)) * (CH >> 5);
  int ca = c0 + (t & 3) * 16;
#pragma unroll
  for (int u = 0; u < 2; u++) {
    int cc = ca + 8 * u;
    size_t addr = ((tb + (cc >> 5)) * 64 + (n & 15) + 16 * ((cc >> 3) & 3)) * 8;
    *(half8*)(dst + addr) = ov[u];
  }
}

// ---------------------------------------------------------------------------
// Kernel 3: Q projection. Block = 64 n x 256 o. Stages its Ht slice (32KB,
// contiguous in tiled layout) to LDS once; all frag reads conflict-free 1KB.
// Output Qt frag-tiled: [b][n>>5][c>>4][64 g][8], g = (n&31) + 32*((c>>3)&1)
// -> per-lane 4 consecutive c = 4 consecutive j = 8B vector store.
// Grid 8*64 = 512.
// ---------------------------------------------------------------------------
__global__ __launch_bounds__(256, 2) void projQ_kernel(
    const _Float16* __restrict__ Ht, const _Float16* __restrict__ Wt,
    const float* __restrict__ bias, _Float16* __restrict__ Qt) {
  int bid = blockIdx.x;
  int b = bid & 7, nt = bid >> 3;
  int t = threadIdx.x, l = t & 63, w = t >> 6;
  int c15 = l & 15, q = l >> 4;

  __shared__ __align__(16) _Float16 hbuf[16384];  // 32KB = 4 ntiles x 8 ks
  half8* hb = (half8*)hbuf;
  {
    const half8* sg = (const half8*)Ht + (size_t)(b * 256 + nt * 4) * 512;
#pragma unroll
    for (int i = 0; i < 8; i++) hb[t + 256 * i] = sg[t + 256 * i];
  }
  __syncthreads();

  const half8* wt8 = (const half8*)Wt;
#pragma unroll
  for (int p = 0; p < 2; p++) {
    int oa = (p * 4 + w) * 2;
    f32x4 acc[2][4] = {};
#pragma unroll
    for (int ks = 0; ks < 8; ks++) {
      half8 af0 = wt8[((size_t)(oa + 0) * 8 + ks) * 64 + l];
      half8 af1 = wt8[((size_t)(oa + 1) * 8 + ks) * 64 + l];
#pragma unroll
      for (int nt2 = 0; nt2 < 4; nt2++) {
        half8 bf = hb[(nt2 * 8 + ks) * 64 + l];
        acc[0][nt2] = MFMA16(af0, bf, acc[0][nt2]);
        acc[1][nt2] = MFMA16(af1, bf, acc[1][nt2]);
      }
    }
#pragma unroll
    for (int j = 0; j < 2; j++) {
      int o4 = (oa + j) * 16 + 4 * q;
      f32x4 bv = *(const f32x4*)(bias + o4);
#pragma unroll
      for (int nt2 = 0; nt2 < 4; nt2++) {
        half4v hv;
#pragma unroll
        for (int r = 0; r < 4; r++) hv[r] = (_Float16)((acc[j][nt2][r] + bv[r]) * 0.0625f);
        size_t addr = ((((size_t)b * 128 + nt * 2 + (nt2 >> 1)) * 16 + (oa + j)) * 64 +
                       (nt2 & 1) * 16 + c15 + 32 * (q >> 1)) * 8 + (q & 1) * 4;
        *(half4v*)(Qt + addr) = hv;
      }
    }
  }
}

// ---------------------------------------------------------------------------
// Kernel 4: fused K+V projection. Block = 64 m x (256 K-o + 256 V-c). Stages
// its h1Tt slice (64KB) once; every LDS frag feeds one K-MFMA (as B-operand,
// A = Wk -> 4 consecutive o/lane -> Kt tiled store) and one V-MFMA (as
// A-operand, B = Wv -> 4 consecutive m/lane -> Vt tiled store, R3-verified
// scatter). Grid 8*64 = 512.
// ---------------------------------------------------------------------------
__global__ __launch_bounds__(256, 2) void projKV_kernel(
    const _Float16* __restrict__ Ht, const _Float16* __restrict__ Wk,
    const _Float16* __restrict__ Wv, const float* __restrict__ kb,
    const float* __restrict__ vb, _Float16* __restrict__ Kt,
    _Float16* __restrict__ Vt) {
  int bid = blockIdx.x;
  int b = bid & 7, mt = bid >> 3;
  int m0 = mt * 64;
  int t = threadIdx.x, l = t & 63, w = t >> 6;
  int c15 = l & 15, q = l >> 4;

  __shared__ __align__(16) _Float16 hbuf[32768];  // 64KB = 4 mtiles x 16 ks
  half8* hb = (half8*)hbuf;
  {
    const half8* sg = (const half8*)Ht + (size_t)(b * 256 + mt * 4) * 1024;
#pragma unroll
    for (int i = 0; i < 16; i++) hb[t + 256 * i] = sg[t + 256 * i];
  }
  __syncthreads();

  const half8* wk8 = (const half8*)Wk;
  const half8* wv8 = (const half8*)Wv;
#pragma unroll
  for (int p = 0; p < 2; p++) {
    int oa = (p * 4 + w) * 2;  // K o-tile pair == V c-tile pair
    f32x4 acck[2][4] = {};
    f32x4 accv[4][2] = {};
#pragma unroll
    for (int ks = 0; ks < 16; ks++) {
      half8 kf0 = wk8[((size_t)(oa + 0) * 16 + ks) * 64 + l];
      half8 kf1 = wk8[((size_t)(oa + 1) * 16 + ks) * 64 + l];
      half8 vf0 = wv8[((size_t)(oa + 0) * 16 + ks) * 64 + l];
      half8 vf1 = wv8[((size_t)(oa + 1) * 16 + ks) * 64 + l];
#pragma unroll
      for (int nt2 = 0; nt2 < 4; nt2++) {
        half8 lf = hb[(nt2 * 16 + ks) * 64 + l];
        acck[0][nt2] = MFMA16(kf0, lf, acck[0][nt2]);
        acck[1][nt2] = MFMA16(kf1, lf, acck[1][nt2]);
        accv[nt2][0] = MFMA16(lf, vf0, accv[nt2][0]);
        accv[nt2][1] = MFMA16(lf, vf1, accv[nt2][1]);
      }
    }
    // ---- K epilogue: Kt[b][m>>5][o>>4][g=(m&31)+32*((o>>3)&1)][j=o&7] ----
#pragma unroll
    for (int j = 0; j < 2; j++) {
      int o4 = (oa + j) * 16 + 4 * q;
      f32x4 bv = *(const f32x4*)(kb + o4);
#pragma unroll
      for (int nt2 = 0; nt2 < 4; nt2++) {
        half4v hv;
#pragma unroll
        for (int r = 0; r < 4; r++) hv[r] = (_Float16)(acck[j][nt2][r] + bv[r]);
        size_t addr = ((((size_t)b * 128 + mt * 2 + (nt2 >> 1)) * 16 + (oa + j)) * 64 +
                       (nt2 & 1) * 16 + c15 + 32 * (q >> 1)) * 8 + (q & 1) * 4;
        *(half4v*)(Kt + addr) = hv;
      }
    }
    // ---- V epilogue: verified Vt scatter (4 consecutive m per lane) ----
#pragma unroll
    for (int nt2 = 0; nt2 < 4; nt2++) {
      int m = m0 + nt2 * 16 + 4 * q;
      size_t mbase = ((size_t)b * 256 + (m >> 4)) * 8;
#pragma unroll
      for (int j = 0; j < 2; j++) {
        int c = (oa + j) * 16 + c15;
        float bs = vb[c];
        half4v hv;
#pragma unroll
        for (int r = 0; r < 4; r++) hv[r] = (_Float16)(accv[nt2][j][r] + bs);
        size_t addr = ((mbase + (c >> 5)) * 64 + (c & 31) + ((q >> 1) << 5)) * 8 + (q & 1) * 4;
        *(half4v*)(Vt + addr) = hv;
      }
    }
  }
}

// ---------------------------------------------------------------------------
// Kernel 5 (R6): pipelined flash attention, all operands frag-tiled.
// Q frags: contiguous 1KB loads from Qt. K: contiguous memcpy Kt->LDS (no
// swizzle; reads lane-contiguous, conflict-free). V: direct tiled global
// (unchanged). P via 8KB LDS (unchanged). Pipeline identical to R5:
// prefetch K(i+1)/V(i) at S-start, ds_write after B0, 2 barriers/iter.
// ---------------------------------------------------------------------------
__global__ __launch_bounds__(256, 2) void attn_kernel(
    const _Float16* __restrict__ Qt, const _Float16* __restrict__ Kt,
    const _Float16* __restrict__ Vt, float* __restrict__ out) {
  int bid = blockIdx.x;
  int b = bid & 7, nt = bid >> 3;
  int n0 = nt * 64;
  int t = threadIdx.x, l = t & 63, w = t >> 6;
  int l31 = l & 31, h = l >> 5;
  int mh = w & 1, nh = w >> 1;

  __shared__ __align__(16) _Float16 kbuf[16384];  // 32KB K tile (2 mtiles)
  __shared__ __align__(16) _Float16 pbuf[4096];   // 8KB P, frag order
  __shared__ float lsw[2][64];
  half8* kb8 = (half8*)kbuf;

  // Q B-frags: contiguous 1KB wave loads from tiled Qt
  half8 qf[16];
  {
    const half8* qt8 = (const half8*)Qt + ((size_t)(b * 128 + nt * 2 + nh) * 16) * 64 + l;
#pragma unroll
    for (int ks = 0; ks < 16; ks++) qf[ks] = qt8[ks * 64];
  }

  const half8* ktb = (const half8*)Kt + (size_t)b * 131072 + t;
  const half8* vt8 = (const half8*)Vt + (size_t)b * 256 * 8 * 64;
  int gb = (l31 ^ h) | (h << 5);  // P-frag granule (unchanged)

  f32x16 acc_o[4] = {};
  float l_part = 0.f;

  // preload K tile 0
  half8 kreg[8];
#pragma unroll
  for (int i = 0; i < 8; i++) kreg[i] = ktb[256 * i];
#pragma unroll
  for (int i = 0; i < 8; i++) kb8[t + 256 * i] = kreg[i];
  __syncthreads();

  for (int it = 0; it < 64; it++) {
    int itn = it < 63 ? it + 1 : 63;
    // prefetch K(it+1); kreg's ds_writes drained by prev iter's B1
#pragma unroll
    for (int i = 0; i < 8; i++) kreg[i] = ktb[itn * 2048 + 256 * i];
    // prefetch V frags ks=0,1
    half8 vf0[8];
#pragma unroll
    for (int u = 0; u < 2; u++)
#pragma unroll
      for (int ct = 0; ct < 4; ct++)
        vf0[u * 4 + ct] = vt8[((size_t)(it * 4 + u) * 8 + (mh * 4 + ct)) * 64 + l];

    // ---- S^T = K Q^T : lane-contiguous conflict-free frag reads ----
    f32x16 s = {};
#pragma unroll
    for (int ks = 0; ks < 16; ks++) {
      half8 kf = kb8[(mh * 16 + ks) * 64 + l];
      s = MFMA32(kf, qf[ks], s);
    }

    // ---- exp + row-sum ----
    half4v pv[4];
#pragma unroll
    for (int k2 = 0; k2 < 4; k2++) {
#pragma unroll
      for (int r = 0; r < 4; r++) {
        float e = __expf(s[4 * k2 + r]);
        l_part += e;
        pv[k2][r] = (_Float16)e;
      }
    }
    __syncthreads();  // B0: kbuf S-reads + pbuf PV-reads complete

    // ---- write P (frag order) and K(it+1) ----
#pragma unroll
    for (int k2 = 0; k2 < 4; k2++) {
      int hm = k2 & 1;
      int tau = nh * 4 + mh * 2 + (k2 >> 1);
      int g = (l31 ^ hm) | (hm << 5);
      *(half4v*)&pbuf[tau * 512 + g * 8 + 4 * h] = pv[k2];
    }
#pragma unroll
    for (int i = 0; i < 8; i++) kb8[t + 256 * i] = kreg[i];
    __syncthreads();  // B1: P(it) + K(it+1) visible; lgkm drained (WAR-safe)

    // ---- O += P V ----
    half8 vf1[8];
#pragma unroll
    for (int u = 0; u < 2; u++)
#pragma unroll
      for (int ct = 0; ct < 4; ct++)
        vf1[u * 4 + ct] = vt8[((size_t)(it * 4 + 2 + u) * 8 + (mh * 4 + ct)) * 64 + l];
#pragma unroll
    for (int ks = 0; ks < 2; ks++) {
      half8 pf = *(const half8*)&pbuf[(nh * 4 + ks) * 512 + gb * 8];
#pragma unroll
      for (int ct = 0; ct < 4; ct++) acc_o[ct] = MFMA32(pf, vf0[ks * 4 + ct], acc_o[ct]);
    }
#pragma unroll
    for (int ks = 2; ks < 4; ks++) {
      half8 pf = *(const half8*)&pbuf[(nh * 4 + ks) * 512 + gb * 8];
#pragma unroll
      for (int ct = 0; ct < 4; ct++) acc_o[ct] = MFMA32(pf, vf1[(ks - 2) * 4 + ct], acc_o[ct]);
    }
  }

  // ---- epilogue (unchanged) ----
  {
    float v = l_part + __shfl_xor(l_part, 32, 64);
    if (l < 32) lsw[mh][nh * 32 + l] = v;
  }
  __syncthreads();
#pragma unroll
  for (int k2 = 0; k2 < 4; k2++) {
    int nb = nh * 32 + 4 * h + 8 * k2;
    f32x4 s0 = *(const f32x4*)&lsw[0][nb];
    f32x4 s1 = *(const f32x4*)&lsw[1][nb];
    f32x4 linv;
#pragma unroll
    for (int r = 0; r < 4; r++) linv[r] = 1.0f / (s0[r] + s1[r]);
#pragma unroll
    for (int ct = 0; ct < 4; ct++) {
      int c = mh * 128 + ct * 32 + l31;
      f32x4 o4;
#pragma unroll
      for (int r = 0; r < 4; r++) o4[r] = acc_o[ct][4 * k2 + r] * linv[r];
      *(f32x4*)(out + ((size_t)(b * 256 + c)) * 4096 + n0 + nb) = o4;
    }
  }
}

// ---------------------------------------------------------------------------
extern "C" void kernel_launch(void* const* d_in, const int* in_sizes, int n_in,
                              void* d_out, int out_size, void* d_ws,
                              size_t ws_size, hipStream_t stream) {
  const float* x = (const float*)d_in[0];
  const float* condA = (const float*)d_in[1];
  const float* gxw = (const float*)d_in[2];
  const float* gxb = (const float*)d_in[3];
  const float* gcw = (const float*)d_in[4];
  const float* gcb = (const float*)d_in[5];
  const float* qw = (const float*)d_in[6];
  const float* qb = (const float*)d_in[7];
  const float* kw = (const float*)d_in[8];
  const float* kb = (const float*)d_in[9];
  const float* vw = (const float*)d_in[10];
  const float* vb = (const float*)d_in[11];
  float* out = (float*)d_out;

  char* ws = (char*)d_ws;
  float* statsx = (float*)(ws);                     // 2048 B
  float* statsc = (float*)(ws + 2048);              // 2048 B
  _Float16* wqt = (_Float16*)(ws + 4096);           // 128 KB (tiled)
  _Float16* wkt = (_Float16*)(ws + 135168);         // 256 KB (tiled)
  _Float16* wvt = (_Float16*)(ws + 397312);         // 256 KB (tiled)
  char* p = ws + 659456;
  _Float16* hxTt = (_Float16*)p; p += (size_t)8 * 4096 * 256 * 2;  // 16 MB tiled
  _Float16* h1Tt = (_Float16*)p; p += (size_t)8 * 4096 * 512 * 2;  // 32 MB tiled
  _Float16* Qt = (_Float16*)p;   p += (size_t)8 * 4096 * 256 * 2;  // 16 MB tiled
  _Float16* Kt = (_Float16*)p;   p += (size_t)8 * 4096 * 256 * 2;  // 16 MB tiled
  _Float16* Vt = (_Float16*)p;                                     // 16 MB tiled

  statswconv_kernel<<<672, 256, 0, stream>>>(x, condA, statsx, statsc,
                                             qw, kw, vw, wqt, wkt, wvt);
  ntrans_kernel<<<6144, 256, 0, stream>>>(x, condA, statsx, statsc,
                                          gxw, gxb, gcw, gcb, hxTt, h1Tt);
  projQ_kernel<<<512, 256, 0, stream>>>(hxTt, wqt, qb, Qt);
  projKV_kernel<<<512, 256, 0, stream>>>(h1Tt, wkt, wvt, kb, vb, Kt, Vt);
  attn_kernel<<<512, 256, 0, stream>>>(Qt, Kt, Vt, out);
}